// Round 3
// baseline (652.461 us; speedup 1.0000x reference)
//
#include <hip/hip_runtime.h>
#include <math.h>

// Problem constants (from setup_inputs): B=16, K=6, H=W=640
#define BB   16
#define KCH  6
#define CH   7          // K+1 channels in pred
#define NN   409600     // H*W
#define N4   102400     // NN/4 (float4 count)
#define EPSF 1e-6f

// Workspace layout (32-bit words). Radix select is 12/12/8 over sortkey.
// At each level we keep counts (all negs) AND dice partial sums
// (negs & tm>0.5): the OHEM text-dice decomposes into suffix sums over bins,
// so no separate textdice pass is needed.
#define S0C_OFF  0u         // [BB][4096] u32 counts, level 0 (key>>20)
#define S0S_OFF  65536u     // [BB][4096][3] f32 sums (pg, pp, gg)
#define S1C_OFF  262144u    // [BB][4096] level 1 ((key>>8)&0xFFF)
#define S1S_OFF  327680u
#define S2C_OFF  524288u    // [BB][256] level 2 (key&0xFF)
#define S2S_OFF  528384u    // [BB][256][3]
#define POS_OFF  540672u
#define NEG_OFF  540688u
#define PRE_OFF  540704u
#define RANK_OFF 540720u
#define UOH_OFF  540736u
#define ACC_OFF  540752u    // [BB][3] f32: suffix sums above selected bins (lvl0+lvl1)
#define APOS_OFF 540800u    // [BB][3] f32: pos-class sums (gt>.5 & tm>.5)
#define ATM_OFF  540848u    // [BB][3] f32: fallback sel=tm sums
#define KERN_OFF 540896u    // [96][3] f32
#define ZERO_END 541184u    // words to memset each launch
#define KM_OFF   541184u    // kmask: [BB][N4] u32 (4 bytes per float4) -- not zeroed
#define WS_WORDS (KM_OFF + BB * N4)   // ~8.7 MB

__device__ __forceinline__ unsigned sortkey(float f) {
    unsigned u = __float_as_uint(f);
    return (u & 0x80000000u) ? ~u : (u | 0x80000000u);
}
__device__ __forceinline__ float fsig(float x) {
    return __builtin_amdgcn_rcpf(1.0f + __expf(-x));
}
__device__ __forceinline__ float wred(float v) {
#pragma unroll
    for (int o = 32; o > 0; o >>= 1) v += __shfl_down(v, o, 64);
    return v;
}
__device__ __forceinline__ unsigned wredu(unsigned v) {
#pragma unroll
    for (int o = 32; o > 0; o >>= 1) v += __shfl_down(v, o, 64);
    return v;
}

// ---------------------------------------------------------------------------
// Pass A: grid (32, BB), depth 12/13 float4 per thread, prefetched.
// Produces: pos/neg counts, level-0 count hist (packed u16 pairs in LDS),
// level-0 dice sums, A_pos, A_tm, kmask.
__global__ __launch_bounds__(256) void k_passA(const float* __restrict__ pred,
                                               const float* __restrict__ gt,
                                               const float* __restrict__ tm,
                                               unsigned* __restrict__ ws) {
    const int b = blockIdx.y;
    const int t = threadIdx.x;
    const float4* p4 = (const float4*)(pred + (size_t)b * CH * NN + (size_t)KCH * NN);
    const float4* g4 = (const float4*)(gt + (size_t)b * NN);
    const float4* m4 = (const float4*)(tm + (size_t)b * NN);
    unsigned* km = ws + KM_OFF + (size_t)b * N4;

    __shared__ unsigned hc[2048];     // packed dual 16-bit counters (4096 bins)
    __shared__ float hs[12288];       // [4096][3] float sums
    for (int i = t; i < 2048; i += 256) hc[i] = 0u;
    for (int i = t; i < 12288; i += 256) hs[i] = 0.f;
    __syncthreads();

    unsigned lpos = 0, lneg = 0;
    float atm0 = 0.f, atm1 = 0.f, atm2 = 0.f;
    float ap0 = 0.f, ap1 = 0.f, ap2 = 0.f;

    auto ELEM = [&](const float4& P, const float4& G, const float4& M, int idx) {
        unsigned kb = 0u;
#pragma unroll
        for (int j = 0; j < 4; j++) {
            float pf = (&P.x)[j], gf = (&G.x)[j], mf = (&M.x)[j];
            unsigned key = sortkey(pf);
            bool neg = (gf <= 0.5f), mok = (mf > 0.5f);
            lneg += neg ? 1u : 0u;
            lpos += (!neg && mok) ? 1u : 0u;
            float sg = fsig(pf);
            float ppm = sg * mf, ggm = gf * mf;
            atm0 += ppm * ggm; atm1 += ppm * ppm; atm2 += ggm * ggm;
            if (mok) {
                if (!neg) { ap0 += sg * gf; ap1 += sg * sg; ap2 += gf * gf; }
                else {
                    unsigned bn = key >> 20;
                    atomicAdd(&hs[bn * 3 + 0], sg * gf);
                    atomicAdd(&hs[bn * 3 + 1], sg * sg);
                    atomicAdd(&hs[bn * 3 + 2], gf * gf);
                }
            }
            if (neg) atomicAdd(&hc[key >> 21], ((key >> 20) & 1u) ? 65536u : 1u);
            kb |= ((pf > 0.f && mok) ? 1u : 0u) << (8 * j);
        }
        km[idx] = kb;
    };

    const int i0 = blockIdx.x * 256 + t;     // [0, 8192)
    int i = i0;
    float4 P = p4[i], G = g4[i], M = m4[i];
#pragma unroll
    for (int it = 0; it < 12; ++it) {
        const bool more = (it < 11);
        const int ni = i + 8192;
        float4 Pn, Gn, Mn;
        if (more) { Pn = p4[ni]; Gn = g4[ni]; Mn = m4[ni]; }
        ELEM(P, G, M, i);
        if (more) { P = Pn; G = Gn; M = Mn; i = ni; }
    }
    {   // guarded tail (blocks x<16 do a 13th chunk)
        const int ix = i0 + 98304;
        if (ix < N4) { float4 Pt = p4[ix], Gt = g4[ix], Mt = m4[ix]; ELEM(Pt, Gt, Mt, ix); }
    }

    lpos = wredu(lpos); lneg = wredu(lneg);
    atm0 = wred(atm0); atm1 = wred(atm1); atm2 = wred(atm2);
    ap0 = wred(ap0); ap1 = wred(ap1); ap2 = wred(ap2);
    if ((t & 63) == 0) {
        atomicAdd(&ws[POS_OFF + b], lpos);
        atomicAdd(&ws[NEG_OFF + b], lneg);
        float* am = (float*)(ws + ATM_OFF) + b * 3;
        atomicAdd(&am[0], atm0); atomicAdd(&am[1], atm1); atomicAdd(&am[2], atm2);
        float* ap = (float*)(ws + APOS_OFF) + b * 3;
        atomicAdd(&ap[0], ap0); atomicAdd(&ap[1], ap1); atomicAdd(&ap[2], ap2);
    }
    __syncthreads();
    unsigned* S0C = ws + S0C_OFF + (size_t)b * 4096u;
    float* S0S = (float*)(ws + S0S_OFF) + (size_t)b * 12288u;
    for (int i2 = t; i2 < 2048; i2 += 256) {
        unsigned v = hc[i2];
        unsigned lo = v & 0xFFFFu, hi = v >> 16;
        if (lo) atomicAdd(&S0C[i2 * 2 + 0], lo);
        if (hi) atomicAdd(&S0C[i2 * 2 + 1], hi);
    }
    for (int i2 = t; i2 < 12288; i2 += 256) {
        float v = hs[i2];
        if (v != 0.f) atomicAdd(&S0S[i2], v);
    }
}

// ---------------------------------------------------------------------------
// Refine 1: bins 19..8 of keys with top-12 == P12. Counts + sums.
__global__ __launch_bounds__(256) void k_ref1(const float* __restrict__ pred,
                                              const float* __restrict__ gt,
                                              const float* __restrict__ tm,
                                              unsigned* __restrict__ ws) {
    const int b = blockIdx.y;
    const int t = threadIdx.x;
    const unsigned P12 = ws[PRE_OFF + b];
    const float4* p4 = (const float4*)(pred + (size_t)b * CH * NN + (size_t)KCH * NN);
    const float4* g4 = (const float4*)(gt + (size_t)b * NN);
    const float4* m4 = (const float4*)(tm + (size_t)b * NN);

    __shared__ unsigned hc[2048];
    __shared__ float hs[12288];
    for (int i = t; i < 2048; i += 256) hc[i] = 0u;
    for (int i = t; i < 12288; i += 256) hs[i] = 0.f;
    __syncthreads();

    auto ELEM = [&](const float4& P, const float4& G, const float4& M) {
#pragma unroll
        for (int j = 0; j < 4; j++) {
            float pf = (&P.x)[j], gf = (&G.x)[j], mf = (&M.x)[j];
            if (gf <= 0.5f) {
                unsigned key = sortkey(pf);
                if ((key >> 20) == P12) {
                    unsigned bn = (key >> 8) & 0xFFFu;
                    atomicAdd(&hc[bn >> 1], (bn & 1u) ? 65536u : 1u);
                    if (mf > 0.5f) {
                        float sg = fsig(pf);
                        atomicAdd(&hs[bn * 3 + 0], sg * gf);
                        atomicAdd(&hs[bn * 3 + 1], sg * sg);
                        atomicAdd(&hs[bn * 3 + 2], gf * gf);
                    }
                }
            }
        }
    };

    const int i0 = blockIdx.x * 256 + t;
    int i = i0;
    float4 P = p4[i], G = g4[i], M = m4[i];
#pragma unroll
    for (int it = 0; it < 12; ++it) {
        const bool more = (it < 11);
        const int ni = i + 8192;
        float4 Pn, Gn, Mn;
        if (more) { Pn = p4[ni]; Gn = g4[ni]; Mn = m4[ni]; }
        ELEM(P, G, M);
        if (more) { P = Pn; G = Gn; M = Mn; i = ni; }
    }
    {
        const int ix = i0 + 98304;
        if (ix < N4) { float4 Pt = p4[ix], Gt = g4[ix], Mt = m4[ix]; ELEM(Pt, Gt, Mt); }
    }

    __syncthreads();
    unsigned* S1C = ws + S1C_OFF + (size_t)b * 4096u;
    float* S1S = (float*)(ws + S1S_OFF) + (size_t)b * 12288u;
    for (int i2 = t; i2 < 2048; i2 += 256) {
        unsigned v = hc[i2];
        unsigned lo = v & 0xFFFFu, hi = v >> 16;
        if (lo) atomicAdd(&S1C[i2 * 2 + 0], lo);
        if (hi) atomicAdd(&S1C[i2 * 2 + 1], hi);
    }
    for (int i2 = t; i2 < 12288; i2 += 256) {
        float v = hs[i2];
        if (v != 0.f) atomicAdd(&S1S[i2], v);
    }
}

// ---------------------------------------------------------------------------
// Refine 2: low 8 bits of keys with top-24 == PRE. Counts + sums.
__global__ __launch_bounds__(256) void k_ref2(const float* __restrict__ pred,
                                              const float* __restrict__ gt,
                                              const float* __restrict__ tm,
                                              unsigned* __restrict__ ws) {
    const int b = blockIdx.y;
    const int t = threadIdx.x;
    const unsigned P24 = ws[PRE_OFF + b];
    const float4* p4 = (const float4*)(pred + (size_t)b * CH * NN + (size_t)KCH * NN);
    const float4* g4 = (const float4*)(gt + (size_t)b * NN);
    const float4* m4 = (const float4*)(tm + (size_t)b * NN);

    __shared__ unsigned hc[256];
    __shared__ float hs[768];
    for (int i = t; i < 256; i += 256) hc[i] = 0u;
    for (int i = t; i < 768; i += 256) hs[i] = 0.f;
    __syncthreads();

    auto ELEM = [&](const float4& P, const float4& G, const float4& M) {
#pragma unroll
        for (int j = 0; j < 4; j++) {
            float pf = (&P.x)[j], gf = (&G.x)[j], mf = (&M.x)[j];
            if (gf <= 0.5f) {
                unsigned key = sortkey(pf);
                if ((key >> 8) == P24) {
                    unsigned bn = key & 0xFFu;
                    atomicAdd(&hc[bn], 1u);
                    if (mf > 0.5f) {
                        float sg = fsig(pf);
                        atomicAdd(&hs[bn * 3 + 0], sg * gf);
                        atomicAdd(&hs[bn * 3 + 1], sg * sg);
                        atomicAdd(&hs[bn * 3 + 2], gf * gf);
                    }
                }
            }
        }
    };

    const int i0 = blockIdx.x * 256 + t;
    int i = i0;
    float4 P = p4[i], G = g4[i], M = m4[i];
#pragma unroll
    for (int it = 0; it < 12; ++it) {
        const bool more = (it < 11);
        const int ni = i + 8192;
        float4 Pn, Gn, Mn;
        if (more) { Pn = p4[ni]; Gn = g4[ni]; Mn = m4[ni]; }
        ELEM(P, G, M);
        if (more) { P = Pn; G = Gn; M = Mn; i = ni; }
    }
    {
        const int ix = i0 + 98304;
        if (ix < N4) { float4 Pt = p4[ix], Gt = g4[ix], Mt = m4[ix]; ELEM(Pt, Gt, Mt); }
    }

    __syncthreads();
    unsigned* S2C = ws + S2C_OFF + (size_t)b * 256u;
    float* S2S = (float*)(ws + S2S_OFF) + (size_t)b * 768u;
    for (int i2 = t; i2 < 256; i2 += 256) {
        unsigned c = hc[i2];
        if (c) atomicAdd(&S2C[i2], c);
    }
    for (int i2 = t; i2 < 768; i2 += 256) {
        float v = hs[i2];
        if (v != 0.f) atomicAdd(&S2S[i2], v);
    }
}

// ---------------------------------------------------------------------------
// Select at level `pass` (0 or 1): pick bin containing rank r from the top,
// update PRE/RANK, and add the strict-suffix dice sums (bins > selected) to ACC.
__global__ __launch_bounds__(256) void k_select(unsigned* __restrict__ ws, int pass) {
    const int b = blockIdx.x;
    const int t = threadIdx.x;
    const unsigned* hist = ws + (pass == 0 ? S0C_OFF : S1C_OFF) + (size_t)b * 4096u;
    const float* sums = (const float*)(ws + (pass == 0 ? S0S_OFF : S1S_OFF)) + (size_t)b * 12288u;
    __shared__ unsigned S[256];
    __shared__ unsigned s_r, s_csel, s_above, s_found, s_selbin;

    if (t == 0) {
        unsigned r;
        if (pass == 0) {
            unsigned pos = ws[POS_OFF + b];
            unsigned ntot = ws[NEG_OFF + b];
            unsigned negnum = min(3u * pos, ntot);
            ws[UOH_OFF + b] = (pos > 0u && negnum > 0u) ? 1u : 0u;
            r = (negnum > 0u) ? negnum : 1u;
        } else {
            r = ws[RANK_OFF + b];
        }
        s_r = r; s_found = 0u; s_selbin = 4096u;
    }
    __syncthreads();
    const unsigned r = s_r;

    unsigned ms = 0;
#pragma unroll 4
    for (int i = 0; i < 16; i++) ms += hist[t * 16 + i];
    S[t] = ms;
    __syncthreads();
#pragma unroll
    for (int off = 1; off < 256; off <<= 1) {
        unsigned v = (t + off < 256) ? S[t + off] : 0u;
        __syncthreads();
        S[t] += v;
        __syncthreads();
    }
    {
        unsigned Sc = S[t], Sc1 = (t == 255) ? 0u : S[t + 1];
        if (Sc >= r && Sc1 < r) { s_csel = (unsigned)t; s_above = Sc1; s_found = 1u; }
    }
    __syncthreads();

    if (t == 0) {
        if (s_found) {
            const unsigned base = s_csel * 16u;
            const unsigned rr = r - s_above;
            unsigned cum = 0, selbin = 0, rem = 1;
            for (int bin = 15; bin >= 0; bin--) {
                unsigned c = hist[base + bin];
                if (cum + c >= rr) { selbin = base + (unsigned)bin; rem = rr - cum; break; }
                cum += c;
            }
            if (pass == 0) ws[PRE_OFF + b] = selbin;
            else ws[PRE_OFF + b] = (ws[PRE_OFF + b] << 12) | selbin;
            ws[RANK_OFF + b] = rem;
            s_selbin = selbin;
        } else {
            ws[PRE_OFF + b] = (pass == 0) ? 0u : (ws[PRE_OFF + b] << 12);
            ws[RANK_OFF + b] = 1u;
        }
    }
    __syncthreads();
    const unsigned selbin = s_selbin;
    float l0 = 0.f, l1 = 0.f, l2 = 0.f;
    for (unsigned bin = t; bin < 4096u; bin += 256u) {
        if (bin > selbin) {
            l0 += sums[bin * 3 + 0];
            l1 += sums[bin * 3 + 1];
            l2 += sums[bin * 3 + 2];
        }
    }
    l0 = wred(l0); l1 = wred(l1); l2 = wred(l2);
    float* acc = (float*)(ws + ACC_OFF) + b * 3;
    if ((t & 63) == 0) {
        atomicAdd(&acc[0], l0); atomicAdd(&acc[1], l1); atomicAdd(&acc[2], l2);
    }
}

// ---------------------------------------------------------------------------
// Kernel-branch dice: grid (20, 96), depth 20, prefetched.
__global__ __launch_bounds__(256) void k_kern2(const float* __restrict__ pred,
                                               const float* __restrict__ gtk,
                                               unsigned* __restrict__ ws) {
    const int bk = blockIdx.y;
    const int b = bk / KCH;
    const int k = bk % KCH;
    const int t = threadIdx.x;
    const float4* pk4 = (const float4*)(pred + ((size_t)b * CH + k) * NN);
    const float4* gk4 = (const float4*)(gtk + ((size_t)b * KCH + k) * NN);
    const unsigned* km = ws + KM_OFF + (size_t)b * N4;

    float a0 = 0.f, a1 = 0.f, a2 = 0.f;
    const int i0 = blockIdx.x * 256 + t;   // [0, 5120)
    int i = i0;
    float4 P = pk4[i], G = gk4[i];
    unsigned KB = km[i];
#pragma unroll
    for (int it = 0; it < 20; ++it) {
        const bool more = (it < 19);
        const int ni = i + 5120;
        float4 Pn, Gn; unsigned KBn;
        if (more) { Pn = pk4[ni]; Gn = gk4[ni]; KBn = km[ni]; }
#pragma unroll
        for (int j = 0; j < 4; j++) {
            float mm = ((KB >> (8 * j)) & 1u) ? 1.f : 0.f;
            float pp = fsig((&P.x)[j]) * mm;
            float gg = (&G.x)[j] * mm;
            a0 += pp * gg; a1 += pp * pp; a2 += gg * gg;
        }
        if (more) { P = Pn; G = Gn; KB = KBn; i = ni; }
    }
    a0 = wred(a0); a1 = wred(a1); a2 = wred(a2);
    float* kf = (float*)(ws + KERN_OFF);
    if ((t & 63) == 0) {
        atomicAdd(&kf[bk * 3 + 0], a0);
        atomicAdd(&kf[bk * 3 + 1], a1);
        atomicAdd(&kf[bk * 3 + 2], a2);
    }
}

// ---------------------------------------------------------------------------
// Final: per-batch level-2 select + suffix sums -> text loss; kern losses; output.
__global__ void k_final(unsigned* __restrict__ ws, float* __restrict__ out) {
    const int t = threadIdx.x;
    __shared__ float red[12];
    __shared__ unsigned s_l8;
    __shared__ float s_lt;
    if (t == 0) s_lt = 0.f;

    for (int b = 0; b < BB; b++) {
        __syncthreads();
        const bool useoh = (ws[UOH_OFF + b] != 0u);
        if (useoh) {
            if (t == 0) {
                unsigned r = ws[RANK_OFF + b];
                const unsigned* C = ws + S2C_OFF + (size_t)b * 256u;
                unsigned cum = 0, l8 = 0;
                for (int bin = 255; bin >= 0; bin--) {
                    unsigned c = C[bin];
                    if (cum + c >= r) { l8 = (unsigned)bin; break; }
                    cum += c;
                }
                s_l8 = l8;
            }
            __syncthreads();
            const float* S = (const float*)(ws + S2S_OFF) + (size_t)b * 768u;
            const unsigned l8 = s_l8;
            float v0 = 0.f, v1 = 0.f, v2 = 0.f;
            if ((unsigned)t >= l8) { v0 = S[t * 3 + 0]; v1 = S[t * 3 + 1]; v2 = S[t * 3 + 2]; }
            v0 = wred(v0); v1 = wred(v1); v2 = wred(v2);
            if ((t & 63) == 0) { int w = t >> 6; red[w * 3 + 0] = v0; red[w * 3 + 1] = v1; red[w * 3 + 2] = v2; }
            __syncthreads();
            if (t == 0) {
                const float* ap = (const float*)(ws + APOS_OFF) + b * 3;
                const float* ac = (const float*)(ws + ACC_OFF) + b * 3;
                float a  = red[0] + red[3] + red[6] + red[9]  + ap[0] + ac[0];
                float p2 = red[1] + red[4] + red[7] + red[10] + ap[1] + ac[1];
                float g2 = red[2] + red[5] + red[8] + red[11] + ap[2] + ac[2];
                s_lt += 1.0f - 2.0f * a / (p2 + g2 + 2.0f * EPSF);
            }
        } else if (t == 0) {
            const float* am = (const float*)(ws + ATM_OFF) + b * 3;
            s_lt += 1.0f - 2.0f * am[0] * 2.0f * 0.5f / (am[1] + am[2] + 2.0f * EPSF);
        }
    }
    __syncthreads();

    float lk = 0.f;
    if (t < 96) {
        const float* kf = (const float*)(ws + KERN_OFF) + t * 3;
        lk = 1.0f - 2.0f * kf[0] / (kf[1] + kf[2] + 2.0f * EPSF);
    }
    lk = wred(lk);
    __shared__ float rk[4];
    if ((t & 63) == 0) rk[t >> 6] = lk;
    __syncthreads();
    if (t == 0) {
        float l_k = (rk[0] + rk[1] + rk[2] + rk[3]) * (1.0f / (KCH * BB));
        float l_t = s_lt * (1.0f / BB);
        out[0] = 0.7f * l_t + 0.3f * l_k;
    }
}

// ---------------------------------------------------------------------------
extern "C" void kernel_launch(void* const* d_in, const int* in_sizes, int n_in,
                              void* d_out, int out_size, void* d_ws, size_t ws_size,
                              hipStream_t stream) {
    const float* pred = (const float*)d_in[0];   // (16,7,640,640)
    const float* gt   = (const float*)d_in[1];   // (16,640,640)
    const float* gtk  = (const float*)d_in[2];   // (16,6,640,640)
    const float* tm   = (const float*)d_in[3];   // (16,640,640)
    float* out = (float*)d_out;
    unsigned* ws = (unsigned*)d_ws;

    hipMemsetAsync(ws, 0, (size_t)ZERO_END * 4, stream);

    dim3 blk(256);
    k_passA<<<dim3(32, BB), blk, 0, stream>>>(pred, gt, tm, ws);
    k_select<<<BB, blk, 0, stream>>>(ws, 0);
    k_ref1<<<dim3(32, BB), blk, 0, stream>>>(pred, gt, tm, ws);
    k_select<<<BB, blk, 0, stream>>>(ws, 1);
    k_ref2<<<dim3(32, BB), blk, 0, stream>>>(pred, gt, tm, ws);
    k_kern2<<<dim3(20, 96), blk, 0, stream>>>(pred, gtk, ws);
    k_final<<<1, 256, 0, stream>>>(ws, out);
}

// Round 4
// 565.635 us; speedup vs baseline: 1.1535x; 1.1535x over previous
//
#include <hip/hip_runtime.h>
#include <math.h>

// Problem constants (from setup_inputs): B=16, K=6, H=W=640
#define BB   16
#define KCH  6
#define CH   7          // K+1 channels in pred
#define NN   409600     // H*W
#define N4   102400     // NN/4 (float4 count)
#define EPSF 1e-6f
#define CAP  8192u      // candidate capacity per batch

// Workspace layout (32-bit words):
#define S0C_OFF  0u         // [BB][4096] u32 counts (12-bit top hist)
#define POS_OFF  65536u
#define NEG_OFF  65552u
#define PRE_OFF  65568u     // selected 12-bit prefix
#define REM_OFF  65584u     // remaining rank within prefix bin
#define UOH_OFF  65600u
#define ACC_OFF  65616u     // [BB][3] f32 suffix dice sums (bins > P12)
#define APOS_OFF 65664u     // [BB][3] f32 pos-class sums
#define ATM_OFF  65712u     // [BB][3] f32 fallback sel=tm sums
#define KERN_OFF 65760u     // [96][3] f32
#define LTEX_OFF 66048u     // [BB] f32 per-batch text loss
#define CCNT_OFF 66064u     // [BB] u32 candidate counts
#define ZERO_END 66080u     // words to memset each launch
#define CAND_OFF 66080u     // [BB][CAP] uint4 candidates {key, sg_m, gf_m, 0}
#define KM_OFF   (66080u + BB * CAP * 4u)          // kmask [BB][N4] u32
#define WS_WORDS (KM_OFF + BB * N4)                // ~8.9 MB

__device__ __forceinline__ unsigned sortkey(float f) {
    unsigned u = __float_as_uint(f);
    return (u & 0x80000000u) ? ~u : (u | 0x80000000u);
}
__device__ __forceinline__ float fsig(float x) {
    return __builtin_amdgcn_rcpf(1.0f + __expf(-x));
}
__device__ __forceinline__ float wred(float v) {
#pragma unroll
    for (int o = 32; o > 0; o >>= 1) v += __shfl_down(v, o, 64);
    return v;
}
__device__ __forceinline__ unsigned wredu(unsigned v) {
#pragma unroll
    for (int o = 32; o > 0; o >>= 1) v += __shfl_down(v, o, 64);
    return v;
}

// ---------------------------------------------------------------------------
// Pass A: grid (50, BB). Dual-stream (2x4 float4/thread). Produces pos/neg
// counts, 4096-bin count hist (16 KB LDS), A_pos, A_tm, kmask.
__global__ __launch_bounds__(256) void k_passA(const float* __restrict__ pred,
                                               const float* __restrict__ gt,
                                               const float* __restrict__ tm,
                                               unsigned* __restrict__ ws) {
    const int b = blockIdx.y;
    const int t = threadIdx.x;
    const float4* p4 = (const float4*)(pred + (size_t)b * CH * NN + (size_t)KCH * NN);
    const float4* g4 = (const float4*)(gt + (size_t)b * NN);
    const float4* m4 = (const float4*)(tm + (size_t)b * NN);
    unsigned* km = ws + KM_OFF + (size_t)b * N4;

    __shared__ unsigned hc[4096];
    for (int i = t; i < 4096; i += 256) hc[i] = 0u;
    __syncthreads();

    unsigned lpos = 0, lneg = 0;
    float atm0 = 0.f, atm1 = 0.f, atm2 = 0.f;
    float ap0 = 0.f, ap1 = 0.f, ap2 = 0.f;

    auto ELEM = [&](const float4& P, const float4& G, const float4& M, int idx) {
        unsigned kb = 0u;
#pragma unroll
        for (int j = 0; j < 4; j++) {
            float pf = (&P.x)[j], gf = (&G.x)[j], mf = (&M.x)[j];
            unsigned key = sortkey(pf);
            bool neg = (gf <= 0.5f), mok = (mf > 0.5f);
            lneg += neg ? 1u : 0u;
            lpos += (!neg && mok) ? 1u : 0u;
            float sg = fsig(pf);
            float ppm = sg * mf, ggm = gf * mf;
            atm0 += ppm * ggm; atm1 += ppm * ppm; atm2 += ggm * ggm;
            if (!neg && mok) { ap0 += sg * gf; ap1 += sg * sg; ap2 += gf * gf; }
            if (neg) atomicAdd(&hc[key >> 20], 1u);
            kb |= ((pf > 0.f && mok) ? 1u : 0u) << (8 * j);
        }
        km[idx] = kb;
    };

    const int base = blockIdx.x * 256 + t;   // [0, 12800)
    int ix = base, iy = base + 51200;
    float4 PX = p4[ix], GX = g4[ix], MX = m4[ix];
    float4 PY = p4[iy], GY = g4[iy], MY = m4[iy];
#pragma unroll
    for (int it = 0; it < 4; ++it) {
        const bool more = (it < 3);
        float4 PXn, GXn, MXn, PYn, GYn, MYn;
        if (more) {
            PXn = p4[ix + 12800]; GXn = g4[ix + 12800]; MXn = m4[ix + 12800];
            PYn = p4[iy + 12800]; GYn = g4[iy + 12800]; MYn = m4[iy + 12800];
        }
        ELEM(PX, GX, MX, ix);
        ELEM(PY, GY, MY, iy);
        if (more) { PX = PXn; GX = GXn; MX = MXn; PY = PYn; GY = GYn; MY = MYn; ix += 12800; iy += 12800; }
    }

    lpos = wredu(lpos); lneg = wredu(lneg);
    atm0 = wred(atm0); atm1 = wred(atm1); atm2 = wred(atm2);
    ap0 = wred(ap0); ap1 = wred(ap1); ap2 = wred(ap2);
    if ((t & 63) == 0) {
        atomicAdd(&ws[POS_OFF + b], lpos);
        atomicAdd(&ws[NEG_OFF + b], lneg);
        float* am = (float*)(ws + ATM_OFF) + b * 3;
        atomicAdd(&am[0], atm0); atomicAdd(&am[1], atm1); atomicAdd(&am[2], atm2);
        float* ap = (float*)(ws + APOS_OFF) + b * 3;
        atomicAdd(&ap[0], ap0); atomicAdd(&ap[1], ap1); atomicAdd(&ap[2], ap2);
    }
    __syncthreads();
    unsigned* S0C = ws + S0C_OFF + (size_t)b * 4096u;
    for (int i = t; i < 4096; i += 256) {
        unsigned c = hc[i];
        if (c) atomicAdd(&S0C[i], c);
    }
}

// ---------------------------------------------------------------------------
// Select level 0: one block per batch, parallel suffix scan over 4096 bins.
__global__ __launch_bounds__(256) void k_select0(unsigned* __restrict__ ws) {
    const int b = blockIdx.x;
    const int t = threadIdx.x;
    const unsigned* hist = ws + S0C_OFF + (size_t)b * 4096u;
    __shared__ unsigned S[256];
    __shared__ unsigned s_r, s_csel, s_above, s_found;

    if (t == 0) {
        unsigned pos = ws[POS_OFF + b];
        unsigned ntot = ws[NEG_OFF + b];
        unsigned negnum = min(3u * pos, ntot);
        ws[UOH_OFF + b] = (pos > 0u && negnum > 0u) ? 1u : 0u;
        s_r = (negnum > 0u) ? negnum : 1u;
        s_found = 0u;
    }
    __syncthreads();
    const unsigned r = s_r;

    unsigned ms = 0;
#pragma unroll 4
    for (int i = 0; i < 16; i++) ms += hist[t * 16 + i];
    S[t] = ms;
    __syncthreads();
#pragma unroll
    for (int off = 1; off < 256; off <<= 1) {
        unsigned v = (t + off < 256) ? S[t + off] : 0u;
        __syncthreads();
        S[t] += v;
        __syncthreads();
    }
    {
        unsigned Sc = S[t], Sc1 = (t == 255) ? 0u : S[t + 1];
        if (Sc >= r && Sc1 < r) { s_csel = (unsigned)t; s_above = Sc1; s_found = 1u; }
    }
    __syncthreads();

    if (t == 0) {
        if (s_found) {
            const unsigned base = s_csel * 16u;
            const unsigned rr = r - s_above;
            unsigned cum = 0;
            for (int bin = 15; bin >= 0; bin--) {
                unsigned c = hist[base + bin];
                if (cum + c >= rr) {
                    ws[PRE_OFF + b] = base + (unsigned)bin;
                    ws[REM_OFF + b] = rr - cum;
                    break;
                }
                cum += c;
            }
        } else {
            ws[PRE_OFF + b] = 0u;
            ws[REM_OFF + b] = 1u;
        }
    }
}

// ---------------------------------------------------------------------------
// Pass B: grid (50, BB). For negatives: bins > P12 accumulate suffix dice
// sums directly; bin == P12 append candidates (wave-aggregated).
__global__ __launch_bounds__(256) void k_passB(const float* __restrict__ pred,
                                               const float* __restrict__ gt,
                                               const float* __restrict__ tm,
                                               unsigned* __restrict__ ws) {
    const int b = blockIdx.y;
    const int t = threadIdx.x;
    const unsigned P12 = ws[PRE_OFF + b];
    const float4* p4 = (const float4*)(pred + (size_t)b * CH * NN + (size_t)KCH * NN);
    const float4* g4 = (const float4*)(gt + (size_t)b * NN);
    const float4* m4 = (const float4*)(tm + (size_t)b * NN);
    uint4* cb = (uint4*)(ws + CAND_OFF) + (size_t)b * CAP;
    unsigned* cc = ws + CCNT_OFF + b;

    float s0 = 0.f, s1 = 0.f, s2 = 0.f;

    auto ELEM = [&](const float4& P, const float4& G, const float4& M) {
#pragma unroll
        for (int j = 0; j < 4; j++) {
            float pf = (&P.x)[j], gf = (&G.x)[j], mf = (&M.x)[j];
            unsigned key = sortkey(pf);
            unsigned bin = key >> 20;
            bool neg = (gf <= 0.5f), mok = (mf > 0.5f);
            if (neg && (bin > P12) && mok) {
                float sg = fsig(pf);
                s0 += sg * gf; s1 += sg * sg; s2 += gf * gf;
            }
            bool iscand = neg && (bin == P12);
            unsigned long long m = __ballot(iscand);
            if (m) {
                int lane = t & 63;
                int leader = __ffsll((unsigned long long)m) - 1;
                unsigned basec = 0;
                int total = __popcll(m);
                if (lane == leader) basec = atomicAdd(cc, (unsigned)total);
                basec = __shfl(basec, leader, 64);
                if (iscand) {
                    unsigned off = (unsigned)__popcll(m & ((1ull << lane) - 1ull));
                    unsigned idx = basec + off;
                    float sg = mok ? fsig(pf) : 0.f;
                    float gfm = mok ? gf : 0.f;
                    if (idx < CAP)
                        cb[idx] = make_uint4(key, __float_as_uint(sg), __float_as_uint(gfm), 0u);
                }
            }
        }
    };

    const int base = blockIdx.x * 256 + t;
    int ix = base, iy = base + 51200;
    float4 PX = p4[ix], GX = g4[ix], MX = m4[ix];
    float4 PY = p4[iy], GY = g4[iy], MY = m4[iy];
#pragma unroll
    for (int it = 0; it < 4; ++it) {
        const bool more = (it < 3);
        float4 PXn, GXn, MXn, PYn, GYn, MYn;
        if (more) {
            PXn = p4[ix + 12800]; GXn = g4[ix + 12800]; MXn = m4[ix + 12800];
            PYn = p4[iy + 12800]; GYn = g4[iy + 12800]; MYn = m4[iy + 12800];
        }
        ELEM(PX, GX, MX);
        ELEM(PY, GY, MY);
        if (more) { PX = PXn; GX = GXn; MX = MXn; PY = PYn; GY = GYn; MY = MYn; ix += 12800; iy += 12800; }
    }

    s0 = wred(s0); s1 = wred(s1); s2 = wred(s2);
    float* acc = (float*)(ws + ACC_OFF) + b * 3;
    if ((t & 63) == 0) {
        atomicAdd(&acc[0], s0); atomicAdd(&acc[1], s1); atomicAdd(&acc[2], s2);
    }
}

// ---------------------------------------------------------------------------
// Kernel-branch dice: grid (10, 96), dual-stream depth 20.
__global__ __launch_bounds__(256) void k_kern2(const float* __restrict__ pred,
                                               const float* __restrict__ gtk,
                                               unsigned* __restrict__ ws) {
    const int bk = blockIdx.y;
    const int b = bk / KCH;
    const int k = bk % KCH;
    const int t = threadIdx.x;
    const float4* pk4 = (const float4*)(pred + ((size_t)b * CH + k) * NN);
    const float4* gk4 = (const float4*)(gtk + ((size_t)b * KCH + k) * NN);
    const unsigned* km = ws + KM_OFF + (size_t)b * N4;

    float a0 = 0.f, a1 = 0.f, a2 = 0.f;
    const int base = blockIdx.x * 256 + t;   // [0, 2560)
    int ix = base, iy = base + 51200;
    float4 PX = pk4[ix], GX = gk4[ix];
    float4 PY = pk4[iy], GY = gk4[iy];
    unsigned KX = km[ix], KY = km[iy];
#pragma unroll
    for (int it = 0; it < 20; ++it) {
        const bool more = (it < 19);
        float4 PXn, GXn, PYn, GYn; unsigned KXn, KYn;
        if (more) {
            PXn = pk4[ix + 2560]; GXn = gk4[ix + 2560]; KXn = km[ix + 2560];
            PYn = pk4[iy + 2560]; GYn = gk4[iy + 2560]; KYn = km[iy + 2560];
        }
#pragma unroll
        for (int j = 0; j < 4; j++) {
            float mm = ((KX >> (8 * j)) & 1u) ? 1.f : 0.f;
            float pp = fsig((&PX.x)[j]) * mm;
            float gg = (&GX.x)[j] * mm;
            a0 += pp * gg; a1 += pp * pp; a2 += gg * gg;
        }
#pragma unroll
        for (int j = 0; j < 4; j++) {
            float mm = ((KY >> (8 * j)) & 1u) ? 1.f : 0.f;
            float pp = fsig((&PY.x)[j]) * mm;
            float gg = (&GY.x)[j] * mm;
            a0 += pp * gg; a1 += pp * pp; a2 += gg * gg;
        }
        if (more) { PX = PXn; GX = GXn; KX = KXn; PY = PYn; GY = GYn; KY = KYn; ix += 2560; iy += 2560; }
    }
    a0 = wred(a0); a1 = wred(a1); a2 = wred(a2);
    float* kf = (float*)(ws + KERN_OFF);
    if ((t & 63) == 0) {
        atomicAdd(&kf[bk * 3 + 0], a0);
        atomicAdd(&kf[bk * 3 + 1], a1);
        atomicAdd(&kf[bk * 3 + 2], a2);
    }
}

// ---------------------------------------------------------------------------
// Final per-batch: exact 2x10-bit radix select over candidates + dice combine.
__global__ __launch_bounds__(256) void k_final(unsigned* __restrict__ ws) {
    const int b = blockIdx.x;
    const int t = threadIdx.x;
    float* lt = (float*)(ws + LTEX_OFF);

    if (ws[UOH_OFF + b] == 0u) {
        if (t == 0) {
            const float* am = (const float*)(ws + ATM_OFF) + b * 3;
            lt[b] = 1.f - 2.f * am[0] / (am[1] + am[2] + 2.f * EPSF);
        }
        return;
    }

    const unsigned n = min(ws[CCNT_OFF + b], CAP);
    const uint4* cb = (const uint4*)(ws + CAND_OFF) + (size_t)b * CAP;
    __shared__ unsigned h[1024];
    __shared__ unsigned S[256];
    __shared__ unsigned s_bin, s_rem, s_above;

    unsigned r = ws[REM_OFF + b];

    // ---- level A: bits 19..10 ----
    for (int i = t; i < 1024; i += 256) h[i] = 0u;
    __syncthreads();
    for (unsigned i = t; i < n; i += 256) atomicAdd(&h[(cb[i].x >> 10) & 0x3FFu], 1u);
    __syncthreads();
    S[t] = h[t * 4] + h[t * 4 + 1] + h[t * 4 + 2] + h[t * 4 + 3];
    __syncthreads();
#pragma unroll
    for (int off = 1; off < 256; off <<= 1) {
        unsigned v = (t + off < 256) ? S[t + off] : 0u;
        __syncthreads();
        S[t] += v;
        __syncthreads();
    }
    {
        unsigned Sc = S[t], Sc1 = (t == 255) ? 0u : S[t + 1];
        if (Sc >= r && Sc1 < r) { s_bin = (unsigned)t; s_above = Sc1; }
    }
    __syncthreads();
    if (t == 0) {
        unsigned base = s_bin * 4u, rr = r - s_above, cum = 0;
        for (int bin = 3; bin >= 0; bin--) {
            unsigned c = h[base + bin];
            if (cum + c >= rr) { s_bin = base + (unsigned)bin; s_rem = rr - cum; break; }
            cum += c;
        }
    }
    __syncthreads();
    const unsigned binA = s_bin;
    r = s_rem;
    __syncthreads();

    // ---- level B: bits 9..0 ----
    for (int i = t; i < 1024; i += 256) h[i] = 0u;
    __syncthreads();
    for (unsigned i = t; i < n; i += 256) {
        unsigned key = cb[i].x;
        if (((key >> 10) & 0x3FFu) == binA) atomicAdd(&h[key & 0x3FFu], 1u);
    }
    __syncthreads();
    S[t] = h[t * 4] + h[t * 4 + 1] + h[t * 4 + 2] + h[t * 4 + 3];
    __syncthreads();
#pragma unroll
    for (int off = 1; off < 256; off <<= 1) {
        unsigned v = (t + off < 256) ? S[t + off] : 0u;
        __syncthreads();
        S[t] += v;
        __syncthreads();
    }
    {
        unsigned Sc = S[t], Sc1 = (t == 255) ? 0u : S[t + 1];
        if (Sc >= r && Sc1 < r) { s_bin = (unsigned)t; s_above = Sc1; }
    }
    __syncthreads();
    if (t == 0) {
        unsigned base = s_bin * 4u, rr = r - s_above, cum = 0;
        for (int bin = 3; bin >= 0; bin--) {
            unsigned c = h[base + bin];
            if (cum + c >= rr) { s_bin = base + (unsigned)bin; break; }
            cum += c;
        }
    }
    __syncthreads();
    const unsigned thr20 = (binA << 10) | s_bin;

    // ---- sum selected candidates (key low-20 >= thr20) ----
    float a0 = 0.f, a1 = 0.f, a2 = 0.f;
    for (unsigned i = t; i < n; i += 256) {
        uint4 c = cb[i];
        if ((c.x & 0xFFFFFu) >= thr20) {
            float sg = __uint_as_float(c.y), gf = __uint_as_float(c.z);
            a0 += sg * gf; a1 += sg * sg; a2 += gf * gf;
        }
    }
    a0 = wred(a0); a1 = wred(a1); a2 = wred(a2);
    __shared__ float R[12];
    if ((t & 63) == 0) { int w = t >> 6; R[w * 3] = a0; R[w * 3 + 1] = a1; R[w * 3 + 2] = a2; }
    __syncthreads();
    if (t == 0) {
        const float* ap = (const float*)(ws + APOS_OFF) + b * 3;
        const float* ac = (const float*)(ws + ACC_OFF) + b * 3;
        float A = R[0] + R[3] + R[6] + R[9]  + ap[0] + ac[0];
        float P = R[1] + R[4] + R[7] + R[10] + ap[1] + ac[1];
        float G = R[2] + R[5] + R[8] + R[11] + ap[2] + ac[2];
        lt[b] = 1.f - 2.f * A / (P + G + 2.f * EPSF);
    }
}

// ---------------------------------------------------------------------------
__global__ void k_out(const unsigned* __restrict__ ws, float* __restrict__ out) {
    const int t = threadIdx.x;  // 64 threads
    const float* kf = (const float*)(ws + KERN_OFF);
    float lk = 0.f;
    for (int i = t; i < KCH * BB; i += 64) {
        float A = kf[i * 3], P = kf[i * 3 + 1], G = kf[i * 3 + 2];
        lk += 1.f - 2.f * A / (P + G + 2.f * EPSF);
    }
    lk = wred(lk);
    const float* lt = (const float*)(ws + LTEX_OFF);
    float l = (t < BB) ? lt[t] : 0.f;
    l = wred(l);
    if (t == 0) out[0] = 0.7f * (l * (1.0f / BB)) + 0.3f * (lk * (1.0f / (KCH * BB)));
}

// ---------------------------------------------------------------------------
extern "C" void kernel_launch(void* const* d_in, const int* in_sizes, int n_in,
                              void* d_out, int out_size, void* d_ws, size_t ws_size,
                              hipStream_t stream) {
    const float* pred = (const float*)d_in[0];   // (16,7,640,640)
    const float* gt   = (const float*)d_in[1];   // (16,640,640)
    const float* gtk  = (const float*)d_in[2];   // (16,6,640,640)
    const float* tm   = (const float*)d_in[3];   // (16,640,640)
    float* out = (float*)d_out;
    unsigned* ws = (unsigned*)d_ws;

    hipMemsetAsync(ws, 0, (size_t)ZERO_END * 4, stream);

    dim3 blk(256);
    k_passA<<<dim3(50, BB), blk, 0, stream>>>(pred, gt, tm, ws);
    k_select0<<<BB, blk, 0, stream>>>(ws);
    k_passB<<<dim3(50, BB), blk, 0, stream>>>(pred, gt, tm, ws);
    k_kern2<<<dim3(10, 96), blk, 0, stream>>>(pred, gtk, ws);
    k_final<<<BB, blk, 0, stream>>>(ws);
    k_out<<<1, 64, 0, stream>>>(ws, out);
}